// Round 14
// baseline (305.540 us; speedup 1.0000x reference)
//
#include <hip/hip_runtime.h>
#include <cstdio>

#define NN 50000
#define NE 800000
#define DD 256
#define CAP 32
#define QCAP 200000
#define WS_NEED 113080000UL

__attribute__((constructor)) static void r26_on_load(void) {
    fprintf(stderr, "R26SO_LOADED\n");
    fflush(stderr);
}

__device__ float b2f(unsigned short u) {
    union { unsigned int i; float f; } c;
    c.i = ((unsigned int)u) << 16;
    return c.f;
}
__device__ float clampf(float v) { return fminf(fmaxf(v, -65504.f), 65504.f); }
__device__ float rdF(const void* p, long long idx, int ff) {
    if (ff) return clampf(b2f(((const unsigned short*)p)[idx]));
    return clampf(((const float*)p)[idx]);
}
__device__ unsigned short f2b_rne(float f) {
    union { float f; unsigned int u; } c;
    c.f = f;
    unsigned int r = (c.u + 0x7FFFu + ((c.u >> 16) & 1u)) >> 16;
    return (unsigned short)r;
}

typedef __attribute__((ext_vector_type(8))) short bf16x8;
typedef __attribute__((ext_vector_type(4))) float f32x4;
typedef __attribute__((ext_vector_type(4))) _Float16 f16x4;
typedef __attribute__((ext_vector_type(8))) _Float16 f16x8;

/* per-block x-dtype detect (2KB read, LDS count) */
__device__ int detect_ff(const unsigned short* xr) {
    __shared__ int dacc;
    if (threadIdx.x == 0) dacc = 0;
    __syncthreads();
    int g = 0;
    for (int j = 0; j < 4; j++) {
        unsigned short u = xr[(threadIdx.x * 4 + j) * 2];
        int e = (u >> 7) & 0xFF;
        if (u == 0 || u == 0x8000 || (e >= 100 && e <= 140)) g++;
    }
    atomicAdd(&dacc, g);
    __syncthreads();
    return dacc >= 922;
}

/* K1: zero (cnt/misc) + dtype detect + W->bf16 + params->fp32. */
__global__ void k_setup(int* cnt, int* misc, const unsigned short* xr,
                        const int* ei, int* flags, const void* W, const void* bias,
                        const void* gamma, const void* beta, unsigned short* Wb,
                        float* pf) {
    int b = blockIdx.x;
    int t = threadIdx.x;
    if (b < 196) {
        int i = b * 256 + t;
        if (i < NN) cnt[i] = 0;
        if (i < 16) misc[i] = 0;
        return;
    }
    if (b == 196) {
        __shared__ int acc2;
        if (t == 0) acc2 = 0;
        int ff = detect_ff(xr); /* has its own syncthreads */
        if (ei[2 * t + 1] != 0) atomicAdd(&acc2, 1);
        __syncthreads();
        if (t == 0) {
            flags[0] = ff;
            flags[1] = (acc2 == 0) ? 1 : 0; /* 1 => int64 edges */
        }
        pf[t] = rdF(bias, t, ff);
        pf[DD + t] = rdF(gamma, t, ff);
        pf[2 * DD + t] = rdF(beta, t, ff);
        return;
    }
    int ff = detect_ff(xr);
    int i = (b - 197) * 256 + t;
    Wb[i] = f2b_rne(rdF(W, i, ff));
}

/* K2a: edge partition into 8 destination-range buckets (R26).
   Fixes k_fill1's cross-XCD line ping-pong (48MB WRITE for 3.2MB payload):
   bucket = c/6250; per-block LDS counts, chunked queue append (coalesced).
   Queue overflow (adversarial skew) falls back to the direct path. */
__global__ __launch_bounds__(256) void k_parta(const int* raw, const int* flags,
                                               int2* eq, int* qcnt, int* cnt,
                                               int* csrc, int* ovf, int* novf) {
    __shared__ int lcnt[8];
    __shared__ int lbase[8];
    int t = threadIdx.x;
    if (t < 8) lcnt[t] = 0;
    __syncthreads();
    int e = blockIdx.x * 256 + t;
    int valid = 0, r = 0, c = 0, b = 0, pos = 0;
    if (e < NE) {
        int f = flags[1];
        r = f ? raw[2 * e] : raw[e];
        c = f ? raw[2 * (NE + e)] : raw[NE + e];
        if ((unsigned int)c < NN && (unsigned int)r < NN) {
            valid = 1;
            b = c / 6250; /* 0..7 */
            pos = atomicAdd(&lcnt[b], 1);
        }
    }
    __syncthreads();
    if (t < 8) lbase[t] = atomicAdd(&qcnt[t], lcnt[t]);
    __syncthreads();
    if (valid) {
        int idx = lbase[b] + pos;
        if (idx < QCAP) {
            int2 p;
            p.x = c;
            p.y = r;
            eq[b * QCAP + idx] = p;
        } else { /* rare fallback: direct fill */
            int slot = atomicAdd(&cnt[c], 1);
            if (slot < CAP) {
                csrc[c * CAP + slot] = r;
            } else {
                int o = atomicAdd(novf, 1);
                ovf[2 * o] = c;
                ovf[2 * o + 1] = r;
            }
        }
    }
}

/* K2b: bucketed CSR fill. Block bid&7==k handles bucket k only; with
   round-robin block->XCD dispatch, all atomics/stores for a cnt/csrc
   line come from ONE XCD -> lines stay L2-resident (no ping-pong). */
__global__ __launch_bounds__(256) void k_fillb(const int2* eq, const int* qcnt,
                                               int* cnt, int* csrc, int* ovf,
                                               int* novf) {
    int k = blockIdx.x & 7;
    int s = blockIdx.x >> 3; /* 0..390 */
    int n = qcnt[k];
    if (n > QCAP) n = QCAP;
    for (int i = s * 256 + threadIdx.x; i < n; i += 391 * 256) {
        int2 p = eq[k * QCAP + i];
        int slot = atomicAdd(&cnt[p.x], 1);
        if (slot < CAP) {
            csrc[p.x * CAP + slot] = p.y;
        } else {
            int o = atomicAdd(novf, 1);
            ovf[2 * o] = p.x;
            ovf[2 * o + 1] = p.y;
        }
    }
}

/* K3: MFMA GEMM, FULL-W LDS. Block = 1024 thr = 16 waves x 16 rows;
   W (256x256 bf16) in 132 KB LDS (528B pitch). Grid 196, x read once.
   h' = rsqrt(deg+1)[n] * (x @ W^T), fp32 acc, fp16 store. dinv inline
   from cnt (k_dinv kernel deleted).
   C/D: col = lane&15, row = (lane>>4)*4 + reg  (m89-verified mapping) */
#define WP 264 /* LDS row pitch in shorts (512B data + 16B pad) */
__global__ __launch_bounds__(1024) void k_gemm(const void* x, const int* flags,
                                               const unsigned short* Wb,
                                               const int* cnt, _Float16* h) {
    __shared__ unsigned short wlds[256 * WP]; /* 135168 B */
    int t = threadIdx.x;

#pragma unroll
    for (int i = 0; i < 8; i++) {
        int c = t + i * 1024;
        int row = c >> 5;
        int off = (c & 31) * 8;
        bf16x8 v = *(const bf16x8*)(Wb + row * DD + off);
        *(bf16x8*)(&wlds[row * WP + off]) = v;
    }
    __syncthreads();

    int wave = t >> 6;
    int lane = t & 63;
    int rw = blockIdx.x * 16 + wave;
    if (rw >= 3125) return; /* after barrier: safe */
    int r0 = rw * 16;
    int l15 = lane & 15;
    int kq = lane >> 4;

    bf16x8 a[8];
    int ff = flags[0];
    if (ff) {
        const unsigned short* p =
            (const unsigned short*)x + (unsigned long long)(r0 + l15) * DD + kq * 8;
#pragma unroll
        for (int k = 0; k < 8; k++)
            a[k] = *(const bf16x8*)(p + k * 32);
    } else {
        const float* p = (const float*)x + (unsigned long long)(r0 + l15) * DD + kq * 8;
#pragma unroll
        for (int k = 0; k < 8; k++) {
#pragma unroll
            for (int j = 0; j < 8; j++)
                a[k][j] = (short)f2b_rne(p[k * 32 + j]);
        }
    }

    float dv[4];
#pragma unroll
    for (int j = 0; j < 4; j++)
        dv[j] = rsqrtf((float)(cnt[r0 + kq * 4 + j] + 1));

#pragma unroll
    for (int ct = 0; ct < 16; ct++) {
        f32x4 acc = {0.f, 0.f, 0.f, 0.f};
#pragma unroll
        for (int k = 0; k < 8; k++) {
            bf16x8 b = *(const bf16x8*)(&wlds[(ct * 16 + l15) * WP + kq * 8 + k * 32]);
            acc = __builtin_amdgcn_mfma_f32_16x16x32_bf16(a[k], b, acc, 0, 0, 0);
        }
        _Float16* op = h + (unsigned long long)(r0 + kq * 4) * DD + ct * 16 + l15;
#pragma unroll
        for (int j = 0; j < 4; j++)
            op[(unsigned long long)j * DD] = (_Float16)(acc[j] * dv[j]);
    }
}

/* K4: aggregate + bias -> fp16 agg. one node per wave, 8-deep ILP unroll.
   Static base n*CAP; overflow nodes (cnt>CAP) scan the tiny ovf list. */
__global__ __launch_bounds__(256) void g_agg(const _Float16* h, const int* cnt,
                                             const int* csrc, const int* ovf,
                                             const int* novf, const float* pf,
                                             _Float16* agg) {
    int lane = threadIdx.x & 63;
    int n = blockIdx.x * 4 + (threadIdx.x >> 6);
    int f0 = lane * 4;
    int cn = __builtin_amdgcn_readfirstlane(cnt[n]);
    int m = (cn < CAP) ? cn : CAP;
    float dn = rsqrtf((float)(cn + 1));
    f16x4 hv = *(const f16x4*)(h + (unsigned long long)n * DD + f0);
    float a0 = (float)hv[0];
    float a1 = (float)hv[1];
    float a2 = (float)hv[2];
    float a3 = (float)hv[3];
    const int* ip = csrc + n * CAP;
    int k = 0;
    for (; k + 8 <= m; k += 8) {
        int i0 = ip[k + 0], i1 = ip[k + 1], i2 = ip[k + 2], i3 = ip[k + 3];
        int i4 = ip[k + 4], i5 = ip[k + 5], i6 = ip[k + 6], i7 = ip[k + 7];
        f16x4 v0 = *(const f16x4*)(h + (unsigned long long)i0 * DD + f0);
        f16x4 v1 = *(const f16x4*)(h + (unsigned long long)i1 * DD + f0);
        f16x4 v2 = *(const f16x4*)(h + (unsigned long long)i2 * DD + f0);
        f16x4 v3 = *(const f16x4*)(h + (unsigned long long)i3 * DD + f0);
        f16x4 v4 = *(const f16x4*)(h + (unsigned long long)i4 * DD + f0);
        f16x4 v5 = *(const f16x4*)(h + (unsigned long long)i5 * DD + f0);
        f16x4 v6 = *(const f16x4*)(h + (unsigned long long)i6 * DD + f0);
        f16x4 v7 = *(const f16x4*)(h + (unsigned long long)i7 * DD + f0);
        a0 += (((float)v0[0] + (float)v1[0]) + ((float)v2[0] + (float)v3[0])) +
              (((float)v4[0] + (float)v5[0]) + ((float)v6[0] + (float)v7[0]));
        a1 += (((float)v0[1] + (float)v1[1]) + ((float)v2[1] + (float)v3[1])) +
              (((float)v4[1] + (float)v5[1]) + ((float)v6[1] + (float)v7[1]));
        a2 += (((float)v0[2] + (float)v1[2]) + ((float)v2[2] + (float)v3[2])) +
              (((float)v4[2] + (float)v5[2]) + ((float)v6[2] + (float)v7[2]));
        a3 += (((float)v0[3] + (float)v1[3]) + ((float)v2[3] + (float)v3[3])) +
              (((float)v4[3] + (float)v5[3]) + ((float)v6[3] + (float)v7[3]));
    }
    for (; k + 4 <= m; k += 4) {
        int i0 = ip[k + 0], i1 = ip[k + 1], i2 = ip[k + 2], i3 = ip[k + 3];
        f16x4 v0 = *(const f16x4*)(h + (unsigned long long)i0 * DD + f0);
        f16x4 v1 = *(const f16x4*)(h + (unsigned long long)i1 * DD + f0);
        f16x4 v2 = *(const f16x4*)(h + (unsigned long long)i2 * DD + f0);
        f16x4 v3 = *(const f16x4*)(h + (unsigned long long)i3 * DD + f0);
        a0 += ((float)v0[0] + (float)v1[0]) + ((float)v2[0] + (float)v3[0]);
        a1 += ((float)v0[1] + (float)v1[1]) + ((float)v2[1] + (float)v3[1]);
        a2 += ((float)v0[2] + (float)v1[2]) + ((float)v2[2] + (float)v3[2]);
        a3 += ((float)v0[3] + (float)v1[3]) + ((float)v2[3] + (float)v3[3]);
    }
    for (; k < m; k++) {
        int i0 = ip[k];
        f16x4 v0 = *(const f16x4*)(h + (unsigned long long)i0 * DD + f0);
        a0 += (float)v0[0];
        a1 += (float)v0[1];
        a2 += (float)v0[2];
        a3 += (float)v0[3];
    }
    if (cn > CAP) { /* rare: scan overflow list (broadcast loads) */
        int no = __builtin_amdgcn_readfirstlane(*novf);
        for (int i = 0; i < no; i++) {
            if (ovf[2 * i] == n) {
                int r = ovf[2 * i + 1];
                f16x4 v0 = *(const f16x4*)(h + (unsigned long long)r * DD + f0);
                a0 += (float)v0[0];
                a1 += (float)v0[1];
                a2 += (float)v0[2];
                a3 += (float)v0[3];
            }
        }
    }
    f16x4 o;
    o[0] = (_Float16)(dn * a0 + pf[f0 + 0]);
    o[1] = (_Float16)(dn * a1 + pf[f0 + 1]);
    o[2] = (_Float16)(dn * a2 + pf[f0 + 2]);
    o[3] = (_Float16)(dn * a3 + pf[f0 + 3]);
    *(f16x4*)(agg + (unsigned long long)n * DD + f0) = o;
}

/* K5a: per-block partial stats, plain stores (no atomics/fence). */
__global__ __launch_bounds__(256) void k_stats1(const _Float16* agg, float* pstat) {
    __shared__ float ls[2][DD];
    int t = threadIdx.x;
    int rg = t >> 5;  /* row group 0..7 */
    int cg = t & 31;  /* feature octet 0..31 */
    float s[8], s2[8];
#pragma unroll
    for (int j = 0; j < 8; j++) { s[j] = 0.f; s2[j] = 0.f; }
    int row0 = blockIdx.x * 64;
    int rend = row0 + 64;
    if (rend > NN) rend = NN;
    for (int r = row0 + rg; r < rend; r += 8) {
        f16x8 v = *(const f16x8*)(agg + (unsigned long long)r * DD + cg * 8);
#pragma unroll
        for (int j = 0; j < 8; j++) {
            float f = (float)v[j];
            s[j] += f;
            s2[j] += f * f;
        }
    }
    ls[0][t] = 0.f;
    ls[1][t] = 0.f;
    __syncthreads();
#pragma unroll
    for (int j = 0; j < 8; j++) {
        atomicAdd(&ls[0][cg * 8 + j], s[j]);
        atomicAdd(&ls[1][cg * 8 + j], s2[j]);
    }
    __syncthreads();
    float* pb = pstat + (unsigned long long)blockIdx.x * 512;
    pb[t] = ls[0][t];
    pb[256 + t] = ls[1][t];
}

/* K5b: final reduce over 782 partials + fin. 32 blocks. */
__global__ __launch_bounds__(256) void k_stats2(const float* pstat, const float* pf,
                                                float* ss) {
    __shared__ float ls[16][16];
    int t = threadIdx.x;
    int r = t >> 4;
    int c = t & 15;
    int j = blockIdx.x;
    int slot = (c < 8) ? (j * 8 + c) : (256 + j * 8 + (c - 8));
    float acc = 0.f;
    for (int b = r; b < 782; b += 16)
        acc += pstat[(unsigned long long)b * 512 + slot];
    ls[r][c] = acc;
    __syncthreads();
    for (int step = 8; step >= 1; step >>= 1) {
        if (r < step) ls[r][c] += ls[r + step][c];
        __syncthreads();
    }
    if (t < 8) {
        int f = j * 8 + t;
        float sv = ls[0][t];
        float sv2 = ls[0][t + 8];
        float mean = sv * (1.0f / NN);
        float var = fmaxf(sv2 * (1.0f / NN) - mean * mean, 0.f);
        float sc = pf[DD + f] * rsqrtf(var + 1e-5f);
        ss[f] = sc;
        ss[DD + f] = pf[2 * DD + f] - mean * sc;
    }
}

/* K6: BN + ReLU: fp16 agg -> fp32 out. 8 elems/thread, grid 6250. */
__global__ void DenseGCNLayer_2937757631000_kernel(const _Float16* agg, const float* ss,
                                                   float* out) {
    int t = threadIdx.x;
    unsigned long long base =
        (unsigned long long)blockIdx.x * 2048 + (unsigned int)t * 8;
    int f = (int)(base & 255);
    f16x8 v = *(const f16x8*)(agg + base);
    f32x4 o0, o1;
#pragma unroll
    for (int j = 0; j < 4; j++)
        o0[j] = fmaxf(ss[f + j] * (float)v[j] + ss[DD + f + j], 0.f);
#pragma unroll
    for (int j = 0; j < 4; j++)
        o1[j] = fmaxf(ss[f + 4 + j] * (float)v[4 + j] + ss[DD + f + 4 + j], 0.f);
    *(f32x4*)(out + base) = o0;
    *(f32x4*)(out + base + 4) = o1;
}

extern "C" void kernel_launch(void* const* d_in, const int* in_sizes, int n_in,
                              void* d_out, int out_size, void* d_ws, size_t ws_size,
                              hipStream_t stream) {
    const void* x = d_in[0];
    const int* ei = (const int*)d_in[1];
    const void* W = d_in[2];
    const void* bias = d_in[3];
    const void* gamma = d_in[4];
    const void* beta = d_in[5];
    char* ws = (char*)d_ws;
    float* out = (float*)d_out;

    _Float16* h = (_Float16*)(ws + 0UL);          /* 25.6 MB fp16 */
    int2* eq = (int2*)(ws + 25600000UL);          /* 12.8 MB bucket queues */
    _Float16* agg = (_Float16*)(ws + 51200000UL); /* 25.6 MB fp16 */
    int* ovf = (int*)(ws + 80000000UL);           /* 6.4 MB overflow pairs */
    float* pstat = (float*)(ws + 102400000UL);    /* 1.6 MB partial stats */
    int* csrc = (int*)(ws + 104800000UL);         /* 6.4 MB (CAP=32) */
    unsigned short* Wb = (unsigned short*)(ws + 112000000UL); /* 128 KB bf16 */
    int* cnt = (int*)(ws + 112262144UL);
    int* misc = (int*)(ws + 113063936UL); /* [0]=novf, [8..15]=qcnt */
    float* pf = (float*)(ws + 113064960UL);
    float* ss = (float*)(ws + 113070080UL);
    int* flags = (int*)(ws + 113072128UL);

    if (ws_size < WS_NEED) {
        fprintf(stderr, "R26_WS_SMALL %zu\n", ws_size);
        fflush(stderr);
        return;
    }

    k_setup<<<453, 256, 0, stream>>>(cnt, misc, (const unsigned short*)x, ei,
                                     flags, W, bias, gamma, beta, Wb, pf);
    k_parta<<<3125, 256, 0, stream>>>(ei, flags, eq, &misc[8], cnt, csrc, ovf,
                                      &misc[0]);
    k_fillb<<<3128, 256, 0, stream>>>(eq, &misc[8], cnt, csrc, ovf, &misc[0]);
    k_gemm<<<196, 1024, 0, stream>>>(x, flags, Wb, cnt, h);
    g_agg<<<12500, 256, 0, stream>>>(h, cnt, csrc, ovf, &misc[0], pf, agg);
    k_stats1<<<782, 256, 0, stream>>>(agg, pstat);
    k_stats2<<<32, 256, 0, stream>>>(pstat, pf, ss);
    DenseGCNLayer_2937757631000_kernel<<<6250, 256, 0, stream>>>(agg, ss, out);
}